// Round 6
// baseline (578.438 us; speedup 1.0000x reference)
//
#include <hip/hip_runtime.h>

// Problem constants: B=2, T=4096, C=1024, H=16, D=64
constexpr int Bn = 2;
constexpr int Tn = 4096;
constexpr int Cn = 1024;
constexpr int Hn = 16;
constexpr int Dn = 64;

typedef __bf16 bf16x8 __attribute__((ext_vector_type(8)));
typedef float f32x4 __attribute__((ext_vector_type(4)));
typedef unsigned short u16x8 __attribute__((ext_vector_type(8)));

__device__ __forceinline__ unsigned short f2bf(float f) {
  unsigned int u = __float_as_uint(f);
  u += 0x7FFF + ((u >> 16) & 1);   // round-to-nearest-even
  return (unsigned short)(u >> 16);
}

__device__ __forceinline__ unsigned short f2bf_hw(float f) {
  return __builtin_bit_cast(unsigned short, (__bf16)f);   // HW cvt, RNE
}

__device__ __forceinline__ bf16x8 ld_bf8(const unsigned short* p) {
  return __builtin_bit_cast(bf16x8, *(const u16x8*)p);
}

// ---------------- f32 -> bf16 cast (vectorized) ----------------
__global__ void cvt_kernel(const float* __restrict__ in, unsigned short* __restrict__ out, int n4) {
  int i = blockIdx.x * blockDim.x + threadIdx.x;
  if (i >= n4) return;
  float4 v = ((const float4*)in)[i];
  ushort4 o;
  o.x = f2bf(v.x); o.y = f2bf(v.y); o.z = f2bf(v.z); o.w = f2bf(v.w);
  ((ushort4*)out)[i] = o;
}

// ---------------- GEMM: C[M][N] = A[M][K] @ B[N][K]^T ----------------
// MODE 0: f32 output.
// MODE 2: fused qkv epilogue — Q cols (<1024) scaled by 0.125*log2e (fold
//   softmax scale + exp2 conversion into Q, single bf16 rounding); K cols
//   written plain bf16; V cols (>=2048) written TRANSPOSED to vT[b][h][d][T]
//   as packed 8B stores (rr = 4 consecutive t). 1024 % 128 == 0 so each block
//   is entirely Q, K, or V.
template<int MODE>
__global__ __launch_bounds__(256) void gemm_bt(const unsigned short* __restrict__ A,
                                               const unsigned short* __restrict__ Bm,
                                               void* __restrict__ Cout,
                                               unsigned short* __restrict__ vT,
                                               int M, int N, int K) {
  __shared__ __align__(16) unsigned short As[128][64];
  __shared__ __align__(16) unsigned short Bs[128][64];
  const int tid  = threadIdx.x;
  const int wave = tid >> 6;
  const int lane = tid & 63;
  const int wr   = (wave >> 1) * 64;
  const int wc   = (wave & 1) * 64;
  const int lrow = lane & 15;
  const int lk8  = (lane >> 4) << 3;

  const int nbx  = gridDim.x;
  const int nwg  = nbx * gridDim.y;
  const int orig = blockIdx.y * nbx + blockIdx.x;
  const int cid  = (orig & 7) * (nwg >> 3) + (orig >> 3);
  const int row0 = (cid / nbx) * 128;
  const int col0 = (cid % nbx) * 128;

  f32x4 acc[4][4];
  #pragma unroll
  for (int i = 0; i < 4; ++i)
    #pragma unroll
    for (int j = 0; j < 4; ++j)
      acc[i][j] = (f32x4){0.f, 0.f, 0.f, 0.f};

  for (int k0 = 0; k0 < K; k0 += 64) {
    const unsigned short* Ag = A  + (size_t)row0 * K + k0;
    const unsigned short* Bg = Bm + (size_t)col0 * K + k0;
    #pragma unroll
    for (int i = 0; i < 4; ++i) {
      int flat = (i * 256 + tid) * 8;
      int r = flat >> 6, c = flat & 63;
      __builtin_amdgcn_global_load_lds((const __attribute__((address_space(1))) void*)(Ag + (size_t)r * K + c),
                                       (__attribute__((address_space(3))) void*)(&As[r][c]), 16, 0, 0);
    }
    #pragma unroll
    for (int i = 0; i < 4; ++i) {
      int flat = (i * 256 + tid) * 8;
      int r = flat >> 6, c = flat & 63;
      __builtin_amdgcn_global_load_lds((const __attribute__((address_space(1))) void*)(Bg + (size_t)r * K + c),
                                       (__attribute__((address_space(3))) void*)(&Bs[r][c]), 16, 0, 0);
    }
    __syncthreads();

    #pragma unroll
    for (int ks = 0; ks < 2; ++ks) {
      bf16x8 af[4], bfr[4];
      #pragma unroll
      for (int i = 0; i < 4; ++i) af[i]  = ld_bf8(&As[wr + i * 16 + lrow][ks * 32 + lk8]);
      #pragma unroll
      for (int j = 0; j < 4; ++j) bfr[j] = ld_bf8(&Bs[wc + j * 16 + lrow][ks * 32 + lk8]);
      #pragma unroll
      for (int i = 0; i < 4; ++i)
        #pragma unroll
        for (int j = 0; j < 4; ++j)
          acc[i][j] = __builtin_amdgcn_mfma_f32_16x16x32_bf16(af[i], bfr[j], acc[i][j], 0, 0, 0);
    }
    __syncthreads();
  }

  const int rg = (lane >> 4) * 4;
  const int cl = lane & 15;
  if constexpr (MODE == 2) {
    if (col0 >= 2048) {
      // V block -> vT[b][h][d][T], packed over rr (4 consecutive t)
      #pragma unroll
      for (int i = 0; i < 4; ++i)
        #pragma unroll
        for (int j = 0; j < 4; ++j) {
          int gm = row0 + wr + i * 16 + rg;
          int gn = col0 - 2048 + wc + j * 16 + cl;
          int hh = gn >> 6, dd = gn & 63;
          int bb = gm >> 12, tt = gm & 4095;
          ushort4 pk;
          pk.x = f2bf(acc[i][j][0]); pk.y = f2bf(acc[i][j][1]);
          pk.z = f2bf(acc[i][j][2]); pk.w = f2bf(acc[i][j][3]);
          *(ushort4*)(vT + (((size_t)bb * 16 + hh) * 64 + dd) * (size_t)Tn + tt) = pk;
        }
    } else {
      const float qs = (col0 < 1024) ? 0.18033688011112042f : 1.0f;  // log2(e)/8
      #pragma unroll
      for (int i = 0; i < 4; ++i)
        #pragma unroll
        for (int j = 0; j < 4; ++j)
          #pragma unroll
          for (int rr = 0; rr < 4; ++rr) {
            int gm = row0 + wr + i * 16 + rg + rr;
            int gn = col0 + wc + j * 16 + cl;
            ((unsigned short*)Cout)[(size_t)gm * N + gn] = f2bf(acc[i][j][rr] * qs);
          }
    }
  } else {
    #pragma unroll
    for (int i = 0; i < 4; ++i)
      #pragma unroll
      for (int j = 0; j < 4; ++j)
        #pragma unroll
        for (int rr = 0; rr < 4; ++rr) {
          int gm = row0 + wr + i * 16 + rg + rr;
          int gn = col0 + wc + j * 16 + cl;
          ((float*)Cout)[(size_t)gm * N + gn] = acc[i][j][rr];
        }
  }
}

// ---------------- Causal flash attention ----------------
// grid = 1024 blocks (T/128 x B*H), block = 256 (4 waves x 32 q-rows: two
// 16-row fragments u=0,1). KVBLK=64. Each K/V fragment ds_read feeds BOTH
// u-fragments' MFMAs (2x amortization); staging/barrier cost per q-row halved.
// Q arrives pre-scaled by 0.125*log2e (gemm1 epilogue) -> softmax in exp2.
// Ks/Vs: same verified swizzled layouts as R5. Ps: [wave][32 rows][8 slots].
__global__ __launch_bounds__(256) void attn_kernel(const unsigned short* __restrict__ qkv,
                                                   const unsigned short* __restrict__ vT,
                                                   unsigned short* __restrict__ outb) {
  __shared__ __align__(16) unsigned short Ks[2][4096];
  __shared__ __align__(16) unsigned short Vs[2][4096];
  __shared__ __align__(16) unsigned short Ps[4][2048];

  const int tid  = threadIdx.x;
  const int wave = tid >> 6;
  const int lane = tid & 63;
  const int cl   = lane & 15;
  const int g    = lane >> 4;
  const int lk8  = g << 3;
  const int rg   = g * 4;

  // XCD-aware bijective swizzle (1024 % 8 == 0); heavy (large-qt) blocks first.
  const int orig = blockIdx.y * gridDim.x + blockIdx.x;   // 0..1023
  const int cid  = (orig & 7) * 128 + (orig >> 3);
  const int qt   = (31 - (cid & 31)) * 128;
  const int bh   = cid >> 5;
  const int b    = bh >> 4;
  const int h    = bh & 15;

  const unsigned short* qb  = qkv + (size_t)b * Tn * (3 * Cn) + h * Dn;
  const unsigned short* kb  = qb + Cn;
  const unsigned short* vtb = vT + (size_t)bh * Dn * Tn;

  // Q fragments for this wave's 32 rows (two 16-row blocks), already scaled.
  bf16x8 qf[2][2];
  {
    const unsigned short* qr0 = qb + (size_t)(qt + wave * 32 + cl) * (3 * Cn) + lk8;
    qf[0][0] = ld_bf8(qr0);
    qf[0][1] = ld_bf8(qr0 + 32);
    const unsigned short* qr1 = qr0 + (size_t)16 * (3 * Cn);
    qf[1][0] = ld_bf8(qr1);
    qf[1][1] = ld_bf8(qr1 + 32);
  }

  f32x4 oacc[2][4];
  #pragma unroll
  for (int u = 0; u < 2; ++u)
    #pragma unroll
    for (int n = 0; n < 4; ++n) oacc[u][n] = (f32x4){0.f, 0.f, 0.f, 0.f};
  float mrun[2][4], lrun[2][4];
  #pragma unroll
  for (int u = 0; u < 2; ++u)
    #pragma unroll
    for (int rr = 0; rr < 4; ++rr) { mrun[u][rr] = -1e30f; lrun[u][rr] = 0.f; }

  // ---- prologue: stage tile 0 into buffer 0 ----
  #pragma unroll
  for (int i = 0; i < 2; ++i) {
    const int flat = i * 256 + tid;
    const int r    = flat >> 3;
    const int cg   = flat & 7;
    const int sw   = cg ^ (r & 7);
    __builtin_amdgcn_global_load_lds(
        (const __attribute__((address_space(1))) void*)(kb + (size_t)r * (3 * Cn) + sw * 8),
        (__attribute__((address_space(3))) void*)(&Ks[0][flat * 8]), 16, 0, 0);
    __builtin_amdgcn_global_load_lds(
        (const __attribute__((address_space(1))) void*)(vtb + (size_t)r * Tn + sw * 8),
        (__attribute__((address_space(3))) void*)(&Vs[0][flat * 8]), 16, 0, 0);
  }
  __syncthreads();

  const int nkv = qt / 64 + 2;
  for (int kt = 0; kt < nkv; ++kt) {
    const int kv0 = kt * 64;
    const int cur = kt & 1;
    const int nb  = cur ^ 1;
    const bool pre = (kt + 1 < nkv);

    // ---- phase A: issue next tile's staging ----
    if (pre) {
      const int kv1 = kv0 + 64;
      #pragma unroll
      for (int i = 0; i < 2; ++i) {
        const int flat = i * 256 + tid;
        const int r    = flat >> 3;
        const int cg   = flat & 7;
        const int sw   = cg ^ (r & 7);
        __builtin_amdgcn_global_load_lds(
            (const __attribute__((address_space(1))) void*)(kb + (size_t)(kv1 + r) * (3 * Cn) + sw * 8),
            (__attribute__((address_space(3))) void*)(&Ks[nb][flat * 8]), 16, 0, 0);
        __builtin_amdgcn_global_load_lds(
            (const __attribute__((address_space(1))) void*)(vtb + (size_t)r * Tn + kv1 + sw * 8),
            (__attribute__((address_space(3))) void*)(&Vs[nb][flat * 8]), 16, 0, 0);
      }
    }

    // ---- phase B: S = Q @ K^T (each kf feeds both u-fragments) ----
    f32x4 s[2][4];
    #pragma unroll
    for (int u = 0; u < 2; ++u)
      #pragma unroll
      for (int n = 0; n < 4; ++n) s[u][n] = (f32x4){0.f, 0.f, 0.f, 0.f};
    __builtin_amdgcn_s_setprio(1);
    #pragma unroll
    for (int n = 0; n < 4; ++n)
      #pragma unroll
      for (int ks = 0; ks < 2; ++ks) {
        bf16x8 kf = ld_bf8(&Ks[cur][(n * 16 + cl) * 64 + (((ks * 4 + g) ^ (cl & 7)) << 3)]);
        s[0][n] = __builtin_amdgcn_mfma_f32_16x16x32_bf16(qf[0][ks], kf, s[0][n], 0, 0, 0);
        s[1][n] = __builtin_amdgcn_mfma_f32_16x16x32_bf16(qf[1][ks], kf, s[1][n], 0, 0, 0);
      }
    __builtin_amdgcn_s_setprio(0);

    // causal mask (only the last two tiles can straddle the diagonal)
    if (kv0 >= qt) {
      #pragma unroll
      for (int u = 0; u < 2; ++u)
        #pragma unroll
        for (int n = 0; n < 4; ++n)
          #pragma unroll
          for (int rr = 0; rr < 4; ++rr) {
            int qg = qt + wave * 32 + u * 16 + rg + rr;
            int kg = kv0 + n * 16 + cl;
            if (kg > qg) s[u][n][rr] = -1e30f;
          }
    }

    // ---- online softmax (base-2; per-lane partial denominators) ----
    float pmax[2][4];
    #pragma unroll
    for (int u = 0; u < 2; ++u)
      #pragma unroll
      for (int rr = 0; rr < 4; ++rr) {
        float mx = fmaxf(fmaxf(s[u][0][rr], s[u][1][rr]), fmaxf(s[u][2][rr], s[u][3][rr]));
        mx = fmaxf(mx, __shfl_xor(mx, 1));
        mx = fmaxf(mx, __shfl_xor(mx, 2));
        mx = fmaxf(mx, __shfl_xor(mx, 4));
        mx = fmaxf(mx, __shfl_xor(mx, 8));
        pmax[u][rr] = mx;
      }
    bool need = false;
    #pragma unroll
    for (int u = 0; u < 2; ++u)
      #pragma unroll
      for (int rr = 0; rr < 4; ++rr) need = need || (pmax[u][rr] > mrun[u][rr]);
    if (__any(need)) {
      #pragma unroll
      for (int u = 0; u < 2; ++u)
        #pragma unroll
        for (int rr = 0; rr < 4; ++rr) {
          float mnew  = fmaxf(mrun[u][rr], pmax[u][rr]);
          float alpha = exp2f(mrun[u][rr] - mnew);
          mrun[u][rr] = mnew;
          float psum = 0.f;
          #pragma unroll
          for (int n = 0; n < 4; ++n) {
            float p = exp2f(s[u][n][rr] - mnew);
            s[u][n][rr] = p;
            psum += p;
          }
          lrun[u][rr] = lrun[u][rr] * alpha + psum;
          #pragma unroll
          for (int n = 0; n < 4; ++n) oacc[u][n][rr] *= alpha;
        }
    } else {   // pmax <= mrun everywhere in wave: alpha == 1 exactly
      #pragma unroll
      for (int u = 0; u < 2; ++u)
        #pragma unroll
        for (int rr = 0; rr < 4; ++rr) {
          float psum = 0.f;
          #pragma unroll
          for (int n = 0; n < 4; ++n) {
            float p = exp2f(s[u][n][rr] - mrun[u][rr]);
            s[u][n][rr] = p;
            psum += p;
          }
          lrun[u][rr] += psum;
        }
    }

    // ---- stage P (both u-fragments; wave-private, slot XOR-swizzled) ----
    #pragma unroll
    for (int u = 0; u < 2; ++u)
      #pragma unroll
      for (int n = 0; n < 4; ++n)
        #pragma unroll
        for (int rr = 0; rr < 4; ++rr) {
          const int row  = u * 16 + rg + rr;
          const int slot = n * 2 + (cl >> 3);
          Ps[wave][row * 64 + ((slot ^ (row & 7)) << 3) + (cl & 7)] = f2bf_hw(s[u][n][rr]);
        }

    // ---- O += P @ V (each vf feeds both u-fragments) ----
    #pragma unroll
    for (int ks = 0; ks < 2; ++ks) {
      bf16x8 pa0 = ld_bf8(&Ps[wave][cl * 64 + (((ks * 4 + g) ^ (cl & 7)) << 3)]);
      bf16x8 pa1 = ld_bf8(&Ps[wave][(16 + cl) * 64 + (((ks * 4 + g) ^ (cl & 7)) << 3)]);
      __builtin_amdgcn_s_setprio(1);
      #pragma unroll
      for (int n = 0; n < 4; ++n) {
        bf16x8 vf = ld_bf8(&Vs[cur][(n * 16 + cl) * 64 + (((ks * 4 + g) ^ (cl & 7)) << 3)]);
        oacc[0][n] = __builtin_amdgcn_mfma_f32_16x16x32_bf16(pa0, vf, oacc[0][n], 0, 0, 0);
        oacc[1][n] = __builtin_amdgcn_mfma_f32_16x16x32_bf16(pa1, vf, oacc[1][n], 0, 0, 0);
      }
      __builtin_amdgcn_s_setprio(0);
    }

    __syncthreads();   // drains vmcnt (next tile's K/V arrival); gates buffer reuse
  }

  // ---- final denominator reduce, normalize, write ----
  #pragma unroll
  for (int u = 0; u < 2; ++u)
    #pragma unroll
    for (int rr = 0; rr < 4; ++rr) {
      lrun[u][rr] += __shfl_xor(lrun[u][rr], 1);
      lrun[u][rr] += __shfl_xor(lrun[u][rr], 2);
      lrun[u][rr] += __shfl_xor(lrun[u][rr], 4);
      lrun[u][rr] += __shfl_xor(lrun[u][rr], 8);
    }
  #pragma unroll
  for (int u = 0; u < 2; ++u)
    #pragma unroll
    for (int rr = 0; rr < 4; ++rr) {
      float inv = 1.0f / lrun[u][rr];
      int t = qt + wave * 32 + u * 16 + rg + rr;
      size_t rowo = ((size_t)b * Tn + t) * Cn + h * Dn;
      #pragma unroll
      for (int n = 0; n < 4; ++n)
        outb[rowo + n * 16 + cl] = f2bf_hw(oacc[u][n][rr] * inv);
    }
}

extern "C" void kernel_launch(void* const* d_in, const int* in_sizes, int n_in,
                              void* d_out, int out_size, void* d_ws, size_t ws_size,
                              hipStream_t stream) {
  const float* x    = (const float*)d_in[0];
  const float* Wqkv = (const float*)d_in[1];
  const float* Wout = (const float*)d_in[2];
  float* y = (float*)d_out;

  // Buffer plan (no growth vs R5):
  //   xb:   x as bf16 for gemm1; DEAD after gemm1 -> reused as attn OUTPUT
  //   vtb:  V transposed [b][h][d][T], written by gemm1 epilogue, read by attn
  unsigned short* xb    = (unsigned short*)d_ws;
  unsigned short* wqkvb = xb    + (size_t)Bn * Tn * Cn;        // 8,388,608
  unsigned short* woutb = wqkvb + (size_t)3 * Cn * Cn;
  unsigned short* qkvb  = woutb + (size_t)Cn * Cn;
  unsigned short* vtb   = qkvb  + (size_t)Bn * Tn * 3 * Cn;    // 8,388,608 elems

  const int M = Bn * Tn;  // 8192

  {
    int n4 = (Bn * Tn * Cn) / 4;
    cvt_kernel<<<(n4 + 255) / 256, 256, 0, stream>>>(x, xb, n4);
  }
  {
    int n4 = (3 * Cn * Cn) / 4;
    cvt_kernel<<<(n4 + 255) / 256, 256, 0, stream>>>(Wqkv, wqkvb, n4);
  }
  {
    int n4 = (Cn * Cn) / 4;
    cvt_kernel<<<(n4 + 255) / 256, 256, 0, stream>>>(Wout, woutb, n4);
  }

  // qkv projection; Q scaled by 0.125*log2e, V written transposed to vtb
  gemm_bt<2><<<dim3(3 * Cn / 128, M / 128), 256, 0, stream>>>(xb, wqkvb, qkvb, vtb, M, 3 * Cn, Cn);

  // attention: out -> xb (xb dead after gemm1)
  attn_kernel<<<dim3(Tn / 128, Bn * Hn), 256, 0, stream>>>(qkvb, vtb, xb);

  // output projection
  gemm_bt<0><<<dim3(Cn / 128, M / 128), 256, 0, stream>>>(xb, woutb, y, nullptr, M, Cn, Cn);

  (void)in_sizes; (void)n_in; (void)out_size; (void)ws_size;
}

// Round 7
// 431.056 us; speedup vs baseline: 1.3419x; 1.3419x over previous
//
#include <hip/hip_runtime.h>

// Problem constants: B=2, T=4096, C=1024, H=16, D=64
constexpr int Bn = 2;
constexpr int Tn = 4096;
constexpr int Cn = 1024;
constexpr int Hn = 16;
constexpr int Dn = 64;

typedef __bf16 bf16x8 __attribute__((ext_vector_type(8)));
typedef float f32x4 __attribute__((ext_vector_type(4)));
typedef unsigned short u16x8 __attribute__((ext_vector_type(8)));

__device__ __forceinline__ unsigned short f2bf(float f) {
  unsigned int u = __float_as_uint(f);
  u += 0x7FFF + ((u >> 16) & 1);   // round-to-nearest-even
  return (unsigned short)(u >> 16);
}

__device__ __forceinline__ unsigned short f2bf_hw(float f) {
  return __builtin_bit_cast(unsigned short, (__bf16)f);   // HW cvt, RNE
}

__device__ __forceinline__ bf16x8 ld_bf8(const unsigned short* p) {
  return __builtin_bit_cast(bf16x8, *(const u16x8*)p);
}

// ---------------- f32 -> bf16 cast (vectorized) ----------------
__global__ void cvt_kernel(const float* __restrict__ in, unsigned short* __restrict__ out, int n4) {
  int i = blockIdx.x * blockDim.x + threadIdx.x;
  if (i >= n4) return;
  float4 v = ((const float4*)in)[i];
  ushort4 o;
  o.x = f2bf(v.x); o.y = f2bf(v.y); o.z = f2bf(v.z); o.w = f2bf(v.w);
  ((ushort4*)out)[i] = o;
}

// ---------------- GEMM: C[M][N] = A[M][K] @ B[N][K]^T ----------------
// MODE 0: f32 output.
// MODE 2: fused qkv epilogue — Q cols (<1024) scaled by 0.125*log2e (fold
//   softmax scale + exp2 conversion into Q, single bf16 rounding); K cols
//   plain bf16; V cols (>=2048) written TRANSPOSED to vT[b][h][d][T] as
//   packed 8B stores. (Verified R6: passed.)
template<int MODE>
__global__ __launch_bounds__(256) void gemm_bt(const unsigned short* __restrict__ A,
                                               const unsigned short* __restrict__ Bm,
                                               void* __restrict__ Cout,
                                               unsigned short* __restrict__ vT,
                                               int M, int N, int K) {
  __shared__ __align__(16) unsigned short As[128][64];
  __shared__ __align__(16) unsigned short Bs[128][64];
  const int tid  = threadIdx.x;
  const int wave = tid >> 6;
  const int lane = tid & 63;
  const int wr   = (wave >> 1) * 64;
  const int wc   = (wave & 1) * 64;
  const int lrow = lane & 15;
  const int lk8  = (lane >> 4) << 3;

  const int nbx  = gridDim.x;
  const int nwg  = nbx * gridDim.y;
  const int orig = blockIdx.y * nbx + blockIdx.x;
  const int cid  = (orig & 7) * (nwg >> 3) + (orig >> 3);
  const int row0 = (cid / nbx) * 128;
  const int col0 = (cid % nbx) * 128;

  f32x4 acc[4][4];
  #pragma unroll
  for (int i = 0; i < 4; ++i)
    #pragma unroll
    for (int j = 0; j < 4; ++j)
      acc[i][j] = (f32x4){0.f, 0.f, 0.f, 0.f};

  for (int k0 = 0; k0 < K; k0 += 64) {
    const unsigned short* Ag = A  + (size_t)row0 * K + k0;
    const unsigned short* Bg = Bm + (size_t)col0 * K + k0;
    #pragma unroll
    for (int i = 0; i < 4; ++i) {
      int flat = (i * 256 + tid) * 8;
      int r = flat >> 6, c = flat & 63;
      __builtin_amdgcn_global_load_lds((const __attribute__((address_space(1))) void*)(Ag + (size_t)r * K + c),
                                       (__attribute__((address_space(3))) void*)(&As[r][c]), 16, 0, 0);
    }
    #pragma unroll
    for (int i = 0; i < 4; ++i) {
      int flat = (i * 256 + tid) * 8;
      int r = flat >> 6, c = flat & 63;
      __builtin_amdgcn_global_load_lds((const __attribute__((address_space(1))) void*)(Bg + (size_t)r * K + c),
                                       (__attribute__((address_space(3))) void*)(&Bs[r][c]), 16, 0, 0);
    }
    __syncthreads();

    #pragma unroll
    for (int ks = 0; ks < 2; ++ks) {
      bf16x8 af[4], bfr[4];
      #pragma unroll
      for (int i = 0; i < 4; ++i) af[i]  = ld_bf8(&As[wr + i * 16 + lrow][ks * 32 + lk8]);
      #pragma unroll
      for (int j = 0; j < 4; ++j) bfr[j] = ld_bf8(&Bs[wc + j * 16 + lrow][ks * 32 + lk8]);
      #pragma unroll
      for (int i = 0; i < 4; ++i)
        #pragma unroll
        for (int j = 0; j < 4; ++j)
          acc[i][j] = __builtin_amdgcn_mfma_f32_16x16x32_bf16(af[i], bfr[j], acc[i][j], 0, 0, 0);
    }
    __syncthreads();
  }

  const int rg = (lane >> 4) * 4;
  const int cl = lane & 15;
  if constexpr (MODE == 2) {
    if (col0 >= 2048) {
      // V block -> vT[b][h][d][T], packed over rr (4 consecutive t)
      #pragma unroll
      for (int i = 0; i < 4; ++i)
        #pragma unroll
        for (int j = 0; j < 4; ++j) {
          int gm = row0 + wr + i * 16 + rg;
          int gn = col0 - 2048 + wc + j * 16 + cl;
          int hh = gn >> 6, dd = gn & 63;
          int bb = gm >> 12, tt = gm & 4095;
          ushort4 pk;
          pk.x = f2bf(acc[i][j][0]); pk.y = f2bf(acc[i][j][1]);
          pk.z = f2bf(acc[i][j][2]); pk.w = f2bf(acc[i][j][3]);
          *(ushort4*)(vT + (((size_t)bb * 16 + hh) * 64 + dd) * (size_t)Tn + tt) = pk;
        }
    } else {
      const float qs = (col0 < 1024) ? 0.18033688011112042f : 1.0f;  // log2(e)/8
      #pragma unroll
      for (int i = 0; i < 4; ++i)
        #pragma unroll
        for (int j = 0; j < 4; ++j)
          #pragma unroll
          for (int rr = 0; rr < 4; ++rr) {
            int gm = row0 + wr + i * 16 + rg + rr;
            int gn = col0 + wc + j * 16 + cl;
            ((unsigned short*)Cout)[(size_t)gm * N + gn] = f2bf(acc[i][j][rr] * qs);
          }
    }
  } else {
    #pragma unroll
    for (int i = 0; i < 4; ++i)
      #pragma unroll
      for (int j = 0; j < 4; ++j)
        #pragma unroll
        for (int rr = 0; rr < 4; ++rr) {
          int gm = row0 + wr + i * 16 + rg + rr;
          int gn = col0 + wc + j * 16 + cl;
          ((float*)Cout)[(size_t)gm * N + gn] = acc[i][j][rr];
        }
  }
}

// ---------------- Causal flash attention (R5 structure, exp2 softmax) ----------------
// grid = 2048 blocks, block = 256 (4 waves x 16 q-rows). KVBLK=64, D=64.
// Q arrives pre-scaled by 0.125*log2e (gemm1 epilogue) -> softmax in exp2.
// Ks/Vs/Ps: verified swizzled layouts (R4/R5: 0 bank conflicts).
__global__ __launch_bounds__(256) void attn_kernel(const unsigned short* __restrict__ qkv,
                                                   const unsigned short* __restrict__ vT,
                                                   unsigned short* __restrict__ outb) {
  __shared__ __align__(16) unsigned short Ks[2][4096];
  __shared__ __align__(16) unsigned short Vs[2][4096];
  __shared__ __align__(16) unsigned short Ps[4][1024];

  const int tid  = threadIdx.x;
  const int wave = tid >> 6;
  const int lane = tid & 63;
  const int cl   = lane & 15;
  const int g    = lane >> 4;
  const int lk8  = g << 3;
  const int rg   = g * 4;

  const int orig = blockIdx.y * gridDim.x + blockIdx.x;   // 0..2047
  const int cid  = (orig & 7) * 256 + (orig >> 3);
  const int qt   = (63 - (cid & 63)) * 64;
  const int bh   = cid >> 6;
  const int b    = bh >> 4;
  const int h    = bh & 15;

  const unsigned short* qb  = qkv + (size_t)b * Tn * (3 * Cn) + h * Dn;
  const unsigned short* kb  = qb + Cn;
  const unsigned short* vtb = vT + (size_t)bh * Dn * Tn;

  // Q fragments (A layout), already scaled by 0.125*log2e in gemm1 epilogue
  bf16x8 qf[2];
  {
    const unsigned short* qr = qb + (size_t)(qt + wave * 16 + cl) * (3 * Cn) + lk8;
    qf[0] = ld_bf8(qr);
    qf[1] = ld_bf8(qr + 32);
  }

  f32x4 oacc[4];
  #pragma unroll
  for (int n = 0; n < 4; ++n) oacc[n] = (f32x4){0.f, 0.f, 0.f, 0.f};
  float mrun[4] = {-1e30f, -1e30f, -1e30f, -1e30f};
  float lrun[4] = {0.f, 0.f, 0.f, 0.f};   // per-lane partial denominators

  // ---- prologue: stage tile 0 into buffer 0 ----
  #pragma unroll
  for (int i = 0; i < 2; ++i) {
    const int flat = i * 256 + tid;
    const int r    = flat >> 3;
    const int cg   = flat & 7;
    const int sw   = cg ^ (r & 7);
    __builtin_amdgcn_global_load_lds(
        (const __attribute__((address_space(1))) void*)(kb + (size_t)r * (3 * Cn) + sw * 8),
        (__attribute__((address_space(3))) void*)(&Ks[0][flat * 8]), 16, 0, 0);
    __builtin_amdgcn_global_load_lds(
        (const __attribute__((address_space(1))) void*)(vtb + (size_t)r * Tn + sw * 8),
        (__attribute__((address_space(3))) void*)(&Vs[0][flat * 8]), 16, 0, 0);
  }
  __syncthreads();

  const int nkv = qt / 64 + 1;
  for (int kt = 0; kt < nkv; ++kt) {
    const int kv0 = kt * 64;
    const int cur = kt & 1;
    const int nb  = cur ^ 1;
    const bool pre = (kt + 1 < nkv);

    // ---- phase A: issue next tile's staging ----
    if (pre) {
      const int kv1 = kv0 + 64;
      #pragma unroll
      for (int i = 0; i < 2; ++i) {
        const int flat = i * 256 + tid;
        const int r    = flat >> 3;
        const int cg   = flat & 7;
        const int sw   = cg ^ (r & 7);
        __builtin_amdgcn_global_load_lds(
            (const __attribute__((address_space(1))) void*)(kb + (size_t)(kv1 + r) * (3 * Cn) + sw * 8),
            (__attribute__((address_space(3))) void*)(&Ks[nb][flat * 8]), 16, 0, 0);
        __builtin_amdgcn_global_load_lds(
            (const __attribute__((address_space(1))) void*)(vtb + (size_t)r * Tn + kv1 + sw * 8),
            (__attribute__((address_space(3))) void*)(&Vs[nb][flat * 8]), 16, 0, 0);
      }
    }

    // ---- phase B: compute tile kt ----
    f32x4 s[4];
    #pragma unroll
    for (int n = 0; n < 4; ++n) s[n] = (f32x4){0.f, 0.f, 0.f, 0.f};
    __builtin_amdgcn_s_setprio(1);
    #pragma unroll
    for (int n = 0; n < 4; ++n)
      #pragma unroll
      for (int ks = 0; ks < 2; ++ks) {
        bf16x8 kf = ld_bf8(&Ks[cur][(n * 16 + cl) * 64 + (((ks * 4 + g) ^ (cl & 7)) << 3)]);
        s[n] = __builtin_amdgcn_mfma_f32_16x16x32_bf16(qf[ks], kf, s[n], 0, 0, 0);
      }
    __builtin_amdgcn_s_setprio(0);

    // causal mask (scale already folded into Q)
    const bool diag = (kv0 == qt);
    if (diag) {
      #pragma unroll
      for (int n = 0; n < 4; ++n)
        #pragma unroll
        for (int rr = 0; rr < 4; ++rr) {
          int ql = wave * 16 + rg + rr;
          int kl = n * 16 + cl;
          if (kl > ql) s[n][rr] = -1e30f;
        }
    }

    // ---- online softmax (base-2) ----
    float pmax[4];
    #pragma unroll
    for (int rr = 0; rr < 4; ++rr) {
      float mx = fmaxf(fmaxf(s[0][rr], s[1][rr]), fmaxf(s[2][rr], s[3][rr]));
      mx = fmaxf(mx, __shfl_xor(mx, 1));
      mx = fmaxf(mx, __shfl_xor(mx, 2));
      mx = fmaxf(mx, __shfl_xor(mx, 4));
      mx = fmaxf(mx, __shfl_xor(mx, 8));
      pmax[rr] = mx;
    }
    const bool need = (pmax[0] > mrun[0]) || (pmax[1] > mrun[1]) ||
                      (pmax[2] > mrun[2]) || (pmax[3] > mrun[3]);
    if (__any(need)) {
      #pragma unroll
      for (int rr = 0; rr < 4; ++rr) {
        float mnew  = fmaxf(mrun[rr], pmax[rr]);
        float alpha = exp2f(mrun[rr] - mnew);
        mrun[rr] = mnew;
        float psum = 0.f;
        #pragma unroll
        for (int n = 0; n < 4; ++n) {
          float p = exp2f(s[n][rr] - mnew);
          s[n][rr] = p;
          psum += p;
        }
        lrun[rr] = lrun[rr] * alpha + psum;
        #pragma unroll
        for (int n = 0; n < 4; ++n) oacc[n][rr] *= alpha;
      }
    } else {   // pmax <= mrun for every row in wave: alpha == 1 exactly
      #pragma unroll
      for (int rr = 0; rr < 4; ++rr) {
        float psum = 0.f;
        #pragma unroll
        for (int n = 0; n < 4; ++n) {
          float p = exp2f(s[n][rr] - mrun[rr]);
          s[n][rr] = p;
          psum += p;
        }
        lrun[rr] += psum;
      }
    }

    // stage P (wave-private, slot XOR-swizzled by row&7)
    #pragma unroll
    for (int n = 0; n < 4; ++n)
      #pragma unroll
      for (int rr = 0; rr < 4; ++rr) {
        const int row  = rg + rr;
        const int slot = n * 2 + (cl >> 3);
        Ps[wave][row * 64 + ((slot ^ (row & 7)) << 3) + (cl & 7)] = f2bf_hw(s[n][rr]);
      }

    // O += P @ V
    #pragma unroll
    for (int ks = 0; ks < 2; ++ks) {
      bf16x8 pa = ld_bf8(&Ps[wave][cl * 64 + (((ks * 4 + g) ^ (cl & 7)) << 3)]);
      __builtin_amdgcn_s_setprio(1);
      #pragma unroll
      for (int n = 0; n < 4; ++n) {
        bf16x8 vf = ld_bf8(&Vs[cur][(n * 16 + cl) * 64 + (((ks * 4 + g) ^ (cl & 7)) << 3)]);
        oacc[n] = __builtin_amdgcn_mfma_f32_16x16x32_bf16(pa, vf, oacc[n], 0, 0, 0);
      }
      __builtin_amdgcn_s_setprio(0);
    }

    __syncthreads();
  }

  // ---- final cross-lane denominator reduce, normalize, write ----
  #pragma unroll
  for (int rr = 0; rr < 4; ++rr) {
    lrun[rr] += __shfl_xor(lrun[rr], 1);
    lrun[rr] += __shfl_xor(lrun[rr], 2);
    lrun[rr] += __shfl_xor(lrun[rr], 4);
    lrun[rr] += __shfl_xor(lrun[rr], 8);
  }
  #pragma unroll
  for (int rr = 0; rr < 4; ++rr) {
    float inv = 1.0f / lrun[rr];
    int t = qt + wave * 16 + rg + rr;
    size_t rowo = ((size_t)b * Tn + t) * Cn + h * Dn;
    #pragma unroll
    for (int n = 0; n < 4; ++n)
      outb[rowo + n * 16 + cl] = f2bf_hw(oacc[n][rr] * inv);
  }
}

extern "C" void kernel_launch(void* const* d_in, const int* in_sizes, int n_in,
                              void* d_out, int out_size, void* d_ws, size_t ws_size,
                              hipStream_t stream) {
  const float* x    = (const float*)d_in[0];
  const float* Wqkv = (const float*)d_in[1];
  const float* Wout = (const float*)d_in[2];
  float* y = (float*)d_out;

  // Buffer plan:
  //   xb:  x as bf16 for gemm1; DEAD after gemm1 -> reused as attn OUTPUT
  //   vtb: V transposed [b][h][d][T], written by gemm1 epilogue, read by attn
  unsigned short* xb    = (unsigned short*)d_ws;
  unsigned short* wqkvb = xb    + (size_t)Bn * Tn * Cn;
  unsigned short* woutb = wqkvb + (size_t)3 * Cn * Cn;
  unsigned short* qkvb  = woutb + (size_t)Cn * Cn;
  unsigned short* vtb   = qkvb  + (size_t)Bn * Tn * 3 * Cn;

  const int M = Bn * Tn;  // 8192

  {
    int n4 = (Bn * Tn * Cn) / 4;
    cvt_kernel<<<(n4 + 255) / 256, 256, 0, stream>>>(x, xb, n4);
  }
  {
    int n4 = (3 * Cn * Cn) / 4;
    cvt_kernel<<<(n4 + 255) / 256, 256, 0, stream>>>(Wqkv, wqkvb, n4);
  }
  {
    int n4 = (Cn * Cn) / 4;
    cvt_kernel<<<(n4 + 255) / 256, 256, 0, stream>>>(Wout, woutb, n4);
  }

  // qkv projection; Q scaled by 0.125*log2e, V written transposed to vtb
  gemm_bt<2><<<dim3(3 * Cn / 128, M / 128), 256, 0, stream>>>(xb, wqkvb, qkvb, vtb, M, 3 * Cn, Cn);

  // attention: out -> xb (dead after gemm1)
  attn_kernel<<<dim3(Tn / 64, Bn * Hn), 256, 0, stream>>>(qkvb, vtb, xb);

  // output projection
  gemm_bt<0><<<dim3(Cn / 128, M / 128), 256, 0, stream>>>(xb, woutb, y, nullptr, M, Cn, Cn);

  (void)in_sizes; (void)n_in; (void)out_size; (void)ws_size;
}

// Round 8
// 407.570 us; speedup vs baseline: 1.4192x; 1.0576x over previous
//
#include <hip/hip_runtime.h>

// Problem constants: B=2, T=4096, C=1024, H=16, D=64
constexpr int Bn = 2;
constexpr int Tn = 4096;
constexpr int Cn = 1024;
constexpr int Hn = 16;
constexpr int Dn = 64;

typedef __bf16 bf16x8 __attribute__((ext_vector_type(8)));
typedef float f32x4 __attribute__((ext_vector_type(4)));
typedef unsigned short u16x8 __attribute__((ext_vector_type(8)));

// Raw v_exp_f32 (2^x). exp2f (libm) costs ~5 extra VALU ops/call for edge
// handling — measured as the R5->R7 attn regression (235->260 us).
#if __has_builtin(__builtin_amdgcn_exp2f)
#define EXP2F(x) __builtin_amdgcn_exp2f(x)
#else
#define EXP2F(x) __expf((x) * 0.6931471805599453f)
#endif

__device__ __forceinline__ unsigned short f2bf(float f) {
  unsigned int u = __float_as_uint(f);
  u += 0x7FFF + ((u >> 16) & 1);   // round-to-nearest-even
  return (unsigned short)(u >> 16);
}

__device__ __forceinline__ unsigned short f2bf_hw(float f) {
  return __builtin_bit_cast(unsigned short, (__bf16)f);   // HW cvt, RNE
}

__device__ __forceinline__ bf16x8 ld_bf8(const unsigned short* p) {
  return __builtin_bit_cast(bf16x8, *(const u16x8*)p);
}

// ---------------- f32 -> bf16 cast (vectorized) ----------------
__global__ void cvt_kernel(const float* __restrict__ in, unsigned short* __restrict__ out, int n4) {
  int i = blockIdx.x * blockDim.x + threadIdx.x;
  if (i >= n4) return;
  float4 v = ((const float4*)in)[i];
  ushort4 o;
  o.x = f2bf(v.x); o.y = f2bf(v.y); o.z = f2bf(v.z); o.w = f2bf(v.w);
  ((ushort4*)out)[i] = o;
}

// ---------------- GEMM: C[M][N] = A[M][K] @ B[N][K]^T ----------------
// MODE 0: f32 output.
// MODE 2: fused qkv epilogue — Q cols (<1024) scaled by 0.125*log2e (fold
//   softmax scale + exp2 conversion into Q, single bf16 rounding); K cols
//   plain bf16; V cols (>=2048) written TRANSPOSED to vT[b][h][d][T] as
//   packed 8B stores. (Verified R6/R7.)
template<int MODE>
__global__ __launch_bounds__(256) void gemm_bt(const unsigned short* __restrict__ A,
                                               const unsigned short* __restrict__ Bm,
                                               void* __restrict__ Cout,
                                               unsigned short* __restrict__ vT,
                                               int M, int N, int K) {
  __shared__ __align__(16) unsigned short As[128][64];
  __shared__ __align__(16) unsigned short Bs[128][64];
  const int tid  = threadIdx.x;
  const int wave = tid >> 6;
  const int lane = tid & 63;
  const int wr   = (wave >> 1) * 64;
  const int wc   = (wave & 1) * 64;
  const int lrow = lane & 15;
  const int lk8  = (lane >> 4) << 3;

  const int nbx  = gridDim.x;
  const int nwg  = nbx * gridDim.y;
  const int orig = blockIdx.y * nbx + blockIdx.x;
  const int cid  = (orig & 7) * (nwg >> 3) + (orig >> 3);
  const int row0 = (cid / nbx) * 128;
  const int col0 = (cid % nbx) * 128;

  f32x4 acc[4][4];
  #pragma unroll
  for (int i = 0; i < 4; ++i)
    #pragma unroll
    for (int j = 0; j < 4; ++j)
      acc[i][j] = (f32x4){0.f, 0.f, 0.f, 0.f};

  for (int k0 = 0; k0 < K; k0 += 64) {
    const unsigned short* Ag = A  + (size_t)row0 * K + k0;
    const unsigned short* Bg = Bm + (size_t)col0 * K + k0;
    #pragma unroll
    for (int i = 0; i < 4; ++i) {
      int flat = (i * 256 + tid) * 8;
      int r = flat >> 6, c = flat & 63;
      __builtin_amdgcn_global_load_lds((const __attribute__((address_space(1))) void*)(Ag + (size_t)r * K + c),
                                       (__attribute__((address_space(3))) void*)(&As[r][c]), 16, 0, 0);
    }
    #pragma unroll
    for (int i = 0; i < 4; ++i) {
      int flat = (i * 256 + tid) * 8;
      int r = flat >> 6, c = flat & 63;
      __builtin_amdgcn_global_load_lds((const __attribute__((address_space(1))) void*)(Bg + (size_t)r * K + c),
                                       (__attribute__((address_space(3))) void*)(&Bs[r][c]), 16, 0, 0);
    }
    __syncthreads();

    #pragma unroll
    for (int ks = 0; ks < 2; ++ks) {
      bf16x8 af[4], bfr[4];
      #pragma unroll
      for (int i = 0; i < 4; ++i) af[i]  = ld_bf8(&As[wr + i * 16 + lrow][ks * 32 + lk8]);
      #pragma unroll
      for (int j = 0; j < 4; ++j) bfr[j] = ld_bf8(&Bs[wc + j * 16 + lrow][ks * 32 + lk8]);
      #pragma unroll
      for (int i = 0; i < 4; ++i)
        #pragma unroll
        for (int j = 0; j < 4; ++j)
          acc[i][j] = __builtin_amdgcn_mfma_f32_16x16x32_bf16(af[i], bfr[j], acc[i][j], 0, 0, 0);
    }
    __syncthreads();
  }

  const int rg = (lane >> 4) * 4;
  const int cl = lane & 15;
  if constexpr (MODE == 2) {
    if (col0 >= 2048) {
      // V block -> vT[b][h][d][T], packed over rr (4 consecutive t)
      #pragma unroll
      for (int i = 0; i < 4; ++i)
        #pragma unroll
        for (int j = 0; j < 4; ++j) {
          int gm = row0 + wr + i * 16 + rg;
          int gn = col0 - 2048 + wc + j * 16 + cl;
          int hh = gn >> 6, dd = gn & 63;
          int bb = gm >> 12, tt = gm & 4095;
          ushort4 pk;
          pk.x = f2bf(acc[i][j][0]); pk.y = f2bf(acc[i][j][1]);
          pk.z = f2bf(acc[i][j][2]); pk.w = f2bf(acc[i][j][3]);
          *(ushort4*)(vT + (((size_t)bb * 16 + hh) * 64 + dd) * (size_t)Tn + tt) = pk;
        }
    } else {
      const float qs = (col0 < 1024) ? 0.18033688011112042f : 1.0f;  // log2(e)/8
      #pragma unroll
      for (int i = 0; i < 4; ++i)
        #pragma unroll
        for (int j = 0; j < 4; ++j)
          #pragma unroll
          for (int rr = 0; rr < 4; ++rr) {
            int gm = row0 + wr + i * 16 + rg + rr;
            int gn = col0 + wc + j * 16 + cl;
            ((unsigned short*)Cout)[(size_t)gm * N + gn] = f2bf(acc[i][j][rr] * qs);
          }
    }
  } else {
    #pragma unroll
    for (int i = 0; i < 4; ++i)
      #pragma unroll
      for (int j = 0; j < 4; ++j)
        #pragma unroll
        for (int rr = 0; rr < 4; ++rr) {
          int gm = row0 + wr + i * 16 + rg + rr;
          int gn = col0 + wc + j * 16 + cl;
          ((float*)Cout)[(size_t)gm * N + gn] = acc[i][j][rr];
        }
  }
}

// ---------------- Causal flash attention (R5 structure, HW exp2 softmax) ----------------
// grid = 2048 blocks, block = 256 (4 waves x 16 q-rows). KVBLK=64, D=64.
// Q arrives pre-scaled by 0.125*log2e (gemm1 epilogue) -> softmax is raw v_exp_f32.
// Ks/Vs/Ps: verified swizzled layouts (R4-R7: 0 bank conflicts).
__global__ __launch_bounds__(256) void attn_kernel(const unsigned short* __restrict__ qkv,
                                                   const unsigned short* __restrict__ vT,
                                                   unsigned short* __restrict__ outb) {
  __shared__ __align__(16) unsigned short Ks[2][4096];
  __shared__ __align__(16) unsigned short Vs[2][4096];
  __shared__ __align__(16) unsigned short Ps[4][1024];

  const int tid  = threadIdx.x;
  const int wave = tid >> 6;
  const int lane = tid & 63;
  const int cl   = lane & 15;
  const int g    = lane >> 4;
  const int lk8  = g << 3;
  const int rg   = g * 4;

  const int orig = blockIdx.y * gridDim.x + blockIdx.x;   // 0..2047
  const int cid  = (orig & 7) * 256 + (orig >> 3);
  const int qt   = (63 - (cid & 63)) * 64;
  const int bh   = cid >> 6;
  const int b    = bh >> 4;
  const int h    = bh & 15;

  const unsigned short* qb  = qkv + (size_t)b * Tn * (3 * Cn) + h * Dn;
  const unsigned short* kb  = qb + Cn;
  const unsigned short* vtb = vT + (size_t)bh * Dn * Tn;

  // Q fragments (A layout), already scaled by 0.125*log2e in gemm1 epilogue
  bf16x8 qf[2];
  {
    const unsigned short* qr = qb + (size_t)(qt + wave * 16 + cl) * (3 * Cn) + lk8;
    qf[0] = ld_bf8(qr);
    qf[1] = ld_bf8(qr + 32);
  }

  f32x4 oacc[4];
  #pragma unroll
  for (int n = 0; n < 4; ++n) oacc[n] = (f32x4){0.f, 0.f, 0.f, 0.f};
  float mrun[4] = {-1e30f, -1e30f, -1e30f, -1e30f};
  float lrun[4] = {0.f, 0.f, 0.f, 0.f};   // per-lane partial denominators

  // ---- prologue: stage tile 0 into buffer 0 ----
  #pragma unroll
  for (int i = 0; i < 2; ++i) {
    const int flat = i * 256 + tid;
    const int r    = flat >> 3;
    const int cg   = flat & 7;
    const int sw   = cg ^ (r & 7);
    __builtin_amdgcn_global_load_lds(
        (const __attribute__((address_space(1))) void*)(kb + (size_t)r * (3 * Cn) + sw * 8),
        (__attribute__((address_space(3))) void*)(&Ks[0][flat * 8]), 16, 0, 0);
    __builtin_amdgcn_global_load_lds(
        (const __attribute__((address_space(1))) void*)(vtb + (size_t)r * Tn + sw * 8),
        (__attribute__((address_space(3))) void*)(&Vs[0][flat * 8]), 16, 0, 0);
  }
  __syncthreads();

  const int nkv = qt / 64 + 1;
  for (int kt = 0; kt < nkv; ++kt) {
    const int kv0 = kt * 64;
    const int cur = kt & 1;
    const int nb  = cur ^ 1;
    const bool pre = (kt + 1 < nkv);

    // ---- phase A: issue next tile's staging ----
    if (pre) {
      const int kv1 = kv0 + 64;
      #pragma unroll
      for (int i = 0; i < 2; ++i) {
        const int flat = i * 256 + tid;
        const int r    = flat >> 3;
        const int cg   = flat & 7;
        const int sw   = cg ^ (r & 7);
        __builtin_amdgcn_global_load_lds(
            (const __attribute__((address_space(1))) void*)(kb + (size_t)(kv1 + r) * (3 * Cn) + sw * 8),
            (__attribute__((address_space(3))) void*)(&Ks[nb][flat * 8]), 16, 0, 0);
        __builtin_amdgcn_global_load_lds(
            (const __attribute__((address_space(1))) void*)(vtb + (size_t)r * Tn + kv1 + sw * 8),
            (__attribute__((address_space(3))) void*)(&Vs[nb][flat * 8]), 16, 0, 0);
      }
    }

    // ---- phase B: compute tile kt ----
    f32x4 s[4];
    #pragma unroll
    for (int n = 0; n < 4; ++n) s[n] = (f32x4){0.f, 0.f, 0.f, 0.f};
    __builtin_amdgcn_s_setprio(1);
    #pragma unroll
    for (int n = 0; n < 4; ++n)
      #pragma unroll
      for (int ks = 0; ks < 2; ++ks) {
        bf16x8 kf = ld_bf8(&Ks[cur][(n * 16 + cl) * 64 + (((ks * 4 + g) ^ (cl & 7)) << 3)]);
        s[n] = __builtin_amdgcn_mfma_f32_16x16x32_bf16(qf[ks], kf, s[n], 0, 0, 0);
      }
    __builtin_amdgcn_s_setprio(0);

    // causal mask (scale already folded into Q)
    const bool diag = (kv0 == qt);
    if (diag) {
      #pragma unroll
      for (int n = 0; n < 4; ++n)
        #pragma unroll
        for (int rr = 0; rr < 4; ++rr) {
          int ql = wave * 16 + rg + rr;
          int kl = n * 16 + cl;
          if (kl > ql) s[n][rr] = -1e30f;
        }
    }

    // ---- online softmax (base-2, raw v_exp_f32) ----
    float pmax[4];
    #pragma unroll
    for (int rr = 0; rr < 4; ++rr) {
      float mx = fmaxf(fmaxf(s[0][rr], s[1][rr]), fmaxf(s[2][rr], s[3][rr]));
      mx = fmaxf(mx, __shfl_xor(mx, 1));
      mx = fmaxf(mx, __shfl_xor(mx, 2));
      mx = fmaxf(mx, __shfl_xor(mx, 4));
      mx = fmaxf(mx, __shfl_xor(mx, 8));
      pmax[rr] = mx;
    }
    const bool need = (pmax[0] > mrun[0]) || (pmax[1] > mrun[1]) ||
                      (pmax[2] > mrun[2]) || (pmax[3] > mrun[3]);
    if (__any(need)) {
      #pragma unroll
      for (int rr = 0; rr < 4; ++rr) {
        float mnew  = fmaxf(mrun[rr], pmax[rr]);
        float alpha = EXP2F(mrun[rr] - mnew);
        mrun[rr] = mnew;
        float psum = 0.f;
        #pragma unroll
        for (int n = 0; n < 4; ++n) {
          float p = EXP2F(s[n][rr] - mnew);
          s[n][rr] = p;
          psum += p;
        }
        lrun[rr] = lrun[rr] * alpha + psum;
        #pragma unroll
        for (int n = 0; n < 4; ++n) oacc[n][rr] *= alpha;
      }
    } else {   // pmax <= mrun for every row in wave: alpha == 1 exactly
      #pragma unroll
      for (int rr = 0; rr < 4; ++rr) {
        float psum = 0.f;
        #pragma unroll
        for (int n = 0; n < 4; ++n) {
          float p = EXP2F(s[n][rr] - mrun[rr]);
          s[n][rr] = p;
          psum += p;
        }
        lrun[rr] += psum;
      }
    }

    // stage P (wave-private, slot XOR-swizzled by row&7)
    #pragma unroll
    for (int n = 0; n < 4; ++n)
      #pragma unroll
      for (int rr = 0; rr < 4; ++rr) {
        const int row  = rg + rr;
        const int slot = n * 2 + (cl >> 3);
        Ps[wave][row * 64 + ((slot ^ (row & 7)) << 3) + (cl & 7)] = f2bf_hw(s[n][rr]);
      }

    // O += P @ V
    #pragma unroll
    for (int ks = 0; ks < 2; ++ks) {
      bf16x8 pa = ld_bf8(&Ps[wave][cl * 64 + (((ks * 4 + g) ^ (cl & 7)) << 3)]);
      __builtin_amdgcn_s_setprio(1);
      #pragma unroll
      for (int n = 0; n < 4; ++n) {
        bf16x8 vf = ld_bf8(&Vs[cur][(n * 16 + cl) * 64 + (((ks * 4 + g) ^ (cl & 7)) << 3)]);
        oacc[n] = __builtin_amdgcn_mfma_f32_16x16x32_bf16(pa, vf, oacc[n], 0, 0, 0);
      }
      __builtin_amdgcn_s_setprio(0);
    }

    __syncthreads();
  }

  // ---- final cross-lane denominator reduce, normalize, write ----
  #pragma unroll
  for (int rr = 0; rr < 4; ++rr) {
    lrun[rr] += __shfl_xor(lrun[rr], 1);
    lrun[rr] += __shfl_xor(lrun[rr], 2);
    lrun[rr] += __shfl_xor(lrun[rr], 4);
    lrun[rr] += __shfl_xor(lrun[rr], 8);
  }
  #pragma unroll
  for (int rr = 0; rr < 4; ++rr) {
    float inv = 1.0f / lrun[rr];
    int t = qt + wave * 16 + rg + rr;
    size_t rowo = ((size_t)b * Tn + t) * Cn + h * Dn;
    #pragma unroll
    for (int n = 0; n < 4; ++n)
      outb[rowo + n * 16 + cl] = f2bf_hw(oacc[n][rr] * inv);
  }
}

extern "C" void kernel_launch(void* const* d_in, const int* in_sizes, int n_in,
                              void* d_out, int out_size, void* d_ws, size_t ws_size,
                              hipStream_t stream) {
  const float* x    = (const float*)d_in[0];
  const float* Wqkv = (const float*)d_in[1];
  const float* Wout = (const float*)d_in[2];
  float* y = (float*)d_out;

  // Buffer plan:
  //   xb:  x as bf16 for gemm1; DEAD after gemm1 -> reused as attn OUTPUT
  //   vtb: V transposed [b][h][d][T], written by gemm1 epilogue, read by attn
  unsigned short* xb    = (unsigned short*)d_ws;
  unsigned short* wqkvb = xb    + (size_t)Bn * Tn * Cn;
  unsigned short* woutb = wqkvb + (size_t)3 * Cn * Cn;
  unsigned short* qkvb  = woutb + (size_t)Cn * Cn;
  unsigned short* vtb   = qkvb  + (size_t)Bn * Tn * 3 * Cn;

  const int M = Bn * Tn;  // 8192

  {
    int n4 = (Bn * Tn * Cn) / 4;
    cvt_kernel<<<(n4 + 255) / 256, 256, 0, stream>>>(x, xb, n4);
  }
  {
    int n4 = (3 * Cn * Cn) / 4;
    cvt_kernel<<<(n4 + 255) / 256, 256, 0, stream>>>(Wqkv, wqkvb, n4);
  }
  {
    int n4 = (Cn * Cn) / 4;
    cvt_kernel<<<(n4 + 255) / 256, 256, 0, stream>>>(Wout, woutb, n4);
  }

  // qkv projection; Q scaled by 0.125*log2e, V written transposed to vtb
  gemm_bt<2><<<dim3(3 * Cn / 128, M / 128), 256, 0, stream>>>(xb, wqkvb, qkvb, vtb, M, 3 * Cn, Cn);

  // attention: out -> xb (dead after gemm1)
  attn_kernel<<<dim3(Tn / 64, Bn * Hn), 256, 0, stream>>>(qkvb, vtb, xb);

  // output projection
  gemm_bt<0><<<dim3(Cn / 128, M / 128), 256, 0, stream>>>(xb, woutb, y, nullptr, M, Cn, Cn);

  (void)in_sizes; (void)n_in; (void)out_size; (void)ws_size;
}

// Round 9
// 374.926 us; speedup vs baseline: 1.5428x; 1.0871x over previous
//
#include <hip/hip_runtime.h>

// Problem constants: B=2, T=4096, C=1024, H=16, D=64
constexpr int Bn = 2;
constexpr int Tn = 4096;
constexpr int Cn = 1024;
constexpr int Hn = 16;
constexpr int Dn = 64;

typedef __bf16 bf16x8 __attribute__((ext_vector_type(8)));
typedef float f32x4 __attribute__((ext_vector_type(4)));
typedef unsigned short u16x8 __attribute__((ext_vector_type(8)));

// Raw v_exp_f32 (2^x). libm exp2f costs ~5 extra VALU ops/call (R7 regression).
#if __has_builtin(__builtin_amdgcn_exp2f)
#define EXP2F(x) __builtin_amdgcn_exp2f(x)
#else
#define EXP2F(x) __expf((x) * 0.6931471805599453f)
#endif

__device__ __forceinline__ unsigned short f2bf(float f) {
  unsigned int u = __float_as_uint(f);
  u += 0x7FFF + ((u >> 16) & 1);   // round-to-nearest-even
  return (unsigned short)(u >> 16);
}

__device__ __forceinline__ unsigned short f2bf_hw(float f) {
  return __builtin_bit_cast(unsigned short, (__bf16)f);   // HW cvt, RNE
}

__device__ __forceinline__ bf16x8 ld_bf8(const unsigned short* p) {
  return __builtin_bit_cast(bf16x8, *(const u16x8*)p);
}

// ---------------- f32 -> bf16 cast (vectorized) ----------------
__global__ void cvt_kernel(const float* __restrict__ in, unsigned short* __restrict__ out, int n4) {
  int i = blockIdx.x * blockDim.x + threadIdx.x;
  if (i >= n4) return;
  float4 v = ((const float4*)in)[i];
  ushort4 o;
  o.x = f2bf(v.x); o.y = f2bf(v.y); o.z = f2bf(v.z); o.w = f2bf(v.w);
  ((ushort4*)out)[i] = o;
}

// ---------------- GEMM: C[M][N] = A[M][K] @ B[N][K]^T (unchanged, verified R6-R8) ----------------
template<int MODE>
__global__ __launch_bounds__(256) void gemm_bt(const unsigned short* __restrict__ A,
                                               const unsigned short* __restrict__ Bm,
                                               void* __restrict__ Cout,
                                               unsigned short* __restrict__ vT,
                                               int M, int N, int K) {
  __shared__ __align__(16) unsigned short As[128][64];
  __shared__ __align__(16) unsigned short Bs[128][64];
  const int tid  = threadIdx.x;
  const int wave = tid >> 6;
  const int lane = tid & 63;
  const int wr   = (wave >> 1) * 64;
  const int wc   = (wave & 1) * 64;
  const int lrow = lane & 15;
  const int lk8  = (lane >> 4) << 3;

  const int nbx  = gridDim.x;
  const int nwg  = nbx * gridDim.y;
  const int orig = blockIdx.y * nbx + blockIdx.x;
  const int cid  = (orig & 7) * (nwg >> 3) + (orig >> 3);
  const int row0 = (cid / nbx) * 128;
  const int col0 = (cid % nbx) * 128;

  f32x4 acc[4][4];
  #pragma unroll
  for (int i = 0; i < 4; ++i)
    #pragma unroll
    for (int j = 0; j < 4; ++j)
      acc[i][j] = (f32x4){0.f, 0.f, 0.f, 0.f};

  for (int k0 = 0; k0 < K; k0 += 64) {
    const unsigned short* Ag = A  + (size_t)row0 * K + k0;
    const unsigned short* Bg = Bm + (size_t)col0 * K + k0;
    #pragma unroll
    for (int i = 0; i < 4; ++i) {
      int flat = (i * 256 + tid) * 8;
      int r = flat >> 6, c = flat & 63;
      __builtin_amdgcn_global_load_lds((const __attribute__((address_space(1))) void*)(Ag + (size_t)r * K + c),
                                       (__attribute__((address_space(3))) void*)(&As[r][c]), 16, 0, 0);
    }
    #pragma unroll
    for (int i = 0; i < 4; ++i) {
      int flat = (i * 256 + tid) * 8;
      int r = flat >> 6, c = flat & 63;
      __builtin_amdgcn_global_load_lds((const __attribute__((address_space(1))) void*)(Bg + (size_t)r * K + c),
                                       (__attribute__((address_space(3))) void*)(&Bs[r][c]), 16, 0, 0);
    }
    __syncthreads();

    #pragma unroll
    for (int ks = 0; ks < 2; ++ks) {
      bf16x8 af[4], bfr[4];
      #pragma unroll
      for (int i = 0; i < 4; ++i) af[i]  = ld_bf8(&As[wr + i * 16 + lrow][ks * 32 + lk8]);
      #pragma unroll
      for (int j = 0; j < 4; ++j) bfr[j] = ld_bf8(&Bs[wc + j * 16 + lrow][ks * 32 + lk8]);
      #pragma unroll
      for (int i = 0; i < 4; ++i)
        #pragma unroll
        for (int j = 0; j < 4; ++j)
          acc[i][j] = __builtin_amdgcn_mfma_f32_16x16x32_bf16(af[i], bfr[j], acc[i][j], 0, 0, 0);
    }
    __syncthreads();
  }

  const int rg = (lane >> 4) * 4;
  const int cl = lane & 15;
  if constexpr (MODE == 2) {
    if (col0 >= 2048) {
      #pragma unroll
      for (int i = 0; i < 4; ++i)
        #pragma unroll
        for (int j = 0; j < 4; ++j) {
          int gm = row0 + wr + i * 16 + rg;
          int gn = col0 - 2048 + wc + j * 16 + cl;
          int hh = gn >> 6, dd = gn & 63;
          int bb = gm >> 12, tt = gm & 4095;
          ushort4 pk;
          pk.x = f2bf(acc[i][j][0]); pk.y = f2bf(acc[i][j][1]);
          pk.z = f2bf(acc[i][j][2]); pk.w = f2bf(acc[i][j][3]);
          *(ushort4*)(vT + (((size_t)bb * 16 + hh) * 64 + dd) * (size_t)Tn + tt) = pk;
        }
    } else {
      const float qs = (col0 < 1024) ? 0.18033688011112042f : 1.0f;  // log2(e)/8
      #pragma unroll
      for (int i = 0; i < 4; ++i)
        #pragma unroll
        for (int j = 0; j < 4; ++j)
          #pragma unroll
          for (int rr = 0; rr < 4; ++rr) {
            int gm = row0 + wr + i * 16 + rg + rr;
            int gn = col0 + wc + j * 16 + cl;
            ((unsigned short*)Cout)[(size_t)gm * N + gn] = f2bf(acc[i][j][rr] * qs);
          }
    }
  } else {
    #pragma unroll
    for (int i = 0; i < 4; ++i)
      #pragma unroll
      for (int j = 0; j < 4; ++j)
        #pragma unroll
        for (int rr = 0; rr < 4; ++rr) {
          int gm = row0 + wr + i * 16 + rg + rr;
          int gn = col0 + wc + j * 16 + cl;
          ((float*)Cout)[(size_t)gm * N + gn] = acc[i][j][rr];
        }
  }
}

// ---------------- Causal flash attention (swapped QK^T, lane-local softmax) ----------------
// grid = 2048 blocks, block = 256 (4 waves x 16 q-rows). KVBLK=64, D=64.
// S^T = mfma(K-frag, Q-frag): s[n][rr] = S^T[kv=n*16+rg+rr][q=cl]. All 16 in-lane
// values share one q -> row-max = 15 fmax + 2 shuffles; mrun/lrun/alpha scalar.
// P staged TRANSPOSED into Ps[q=cl][kv] as 4x ds_write_b64, chunk-swizzled
// (chunk' = n ^ (cl&3)); PV reads pa at the matching swizzle (roundtrip verified).
// PV itself + Vs/oacc orientation unchanged from R8.
__global__ __launch_bounds__(256) void attn_kernel(const unsigned short* __restrict__ qkv,
                                                   const unsigned short* __restrict__ vT,
                                                   unsigned short* __restrict__ outb) {
  __shared__ __align__(16) unsigned short Ks[2][4096];
  __shared__ __align__(16) unsigned short Vs[2][4096];
  __shared__ __align__(16) unsigned short Ps[4][1024];

  const int tid  = threadIdx.x;
  const int wave = tid >> 6;
  const int lane = tid & 63;
  const int cl   = lane & 15;
  const int g    = lane >> 4;
  const int lk8  = g << 3;
  const int rg   = g * 4;

  const int orig = blockIdx.y * gridDim.x + blockIdx.x;   // 0..2047
  const int cid  = (orig & 7) * 256 + (orig >> 3);
  const int qt   = (63 - (cid & 63)) * 64;
  const int bh   = cid >> 6;
  const int b    = bh >> 4;
  const int h    = bh & 15;

  const unsigned short* qb  = qkv + (size_t)b * Tn * (3 * Cn) + h * Dn;
  const unsigned short* kb  = qb + Cn;
  const unsigned short* vtb = vT + (size_t)bh * Dn * Tn;

  // Q fragments (row = q = cl, k = d), pre-scaled by 0.125*log2e in gemm1
  bf16x8 qf[2];
  {
    const unsigned short* qr = qb + (size_t)(qt + wave * 16 + cl) * (3 * Cn) + lk8;
    qf[0] = ld_bf8(qr);
    qf[1] = ld_bf8(qr + 32);
  }

  f32x4 oacc[4];
  #pragma unroll
  for (int n = 0; n < 4; ++n) oacc[n] = (f32x4){0.f, 0.f, 0.f, 0.f};
  float mrun = -1e30f;   // per-lane: running max for q=cl
  float lrun = 0.f;      // per-lane partial denominator (this lane's kv slices)

  // ---- prologue: stage tile 0 into buffer 0 ----
  #pragma unroll
  for (int i = 0; i < 2; ++i) {
    const int flat = i * 256 + tid;
    const int r    = flat >> 3;
    const int cg   = flat & 7;
    const int sw   = cg ^ (r & 7);
    __builtin_amdgcn_global_load_lds(
        (const __attribute__((address_space(1))) void*)(kb + (size_t)r * (3 * Cn) + sw * 8),
        (__attribute__((address_space(3))) void*)(&Ks[0][flat * 8]), 16, 0, 0);
    __builtin_amdgcn_global_load_lds(
        (const __attribute__((address_space(1))) void*)(vtb + (size_t)r * Tn + sw * 8),
        (__attribute__((address_space(3))) void*)(&Vs[0][flat * 8]), 16, 0, 0);
  }
  __syncthreads();

  const int nkv = qt / 64 + 1;
  for (int kt = 0; kt < nkv; ++kt) {
    const int kv0 = kt * 64;
    const int cur = kt & 1;
    const int nb  = cur ^ 1;
    const bool pre = (kt + 1 < nkv);

    // ---- phase A: issue next tile's staging ----
    if (pre) {
      const int kv1 = kv0 + 64;
      #pragma unroll
      for (int i = 0; i < 2; ++i) {
        const int flat = i * 256 + tid;
        const int r    = flat >> 3;
        const int cg   = flat & 7;
        const int sw   = cg ^ (r & 7);
        __builtin_amdgcn_global_load_lds(
            (const __attribute__((address_space(1))) void*)(kb + (size_t)(kv1 + r) * (3 * Cn) + sw * 8),
            (__attribute__((address_space(3))) void*)(&Ks[nb][flat * 8]), 16, 0, 0);
        __builtin_amdgcn_global_load_lds(
            (const __attribute__((address_space(1))) void*)(vtb + (size_t)r * Tn + kv1 + sw * 8),
            (__attribute__((address_space(3))) void*)(&Vs[nb][flat * 8]), 16, 0, 0);
      }
    }

    // ---- phase B: S^T = K @ Q^T (swapped args; same fragment reads as R8) ----
    f32x4 s[4];
    #pragma unroll
    for (int n = 0; n < 4; ++n) s[n] = (f32x4){0.f, 0.f, 0.f, 0.f};
    __builtin_amdgcn_s_setprio(1);
    #pragma unroll
    for (int n = 0; n < 4; ++n)
      #pragma unroll
      for (int ks = 0; ks < 2; ++ks) {
        bf16x8 kf = ld_bf8(&Ks[cur][(n * 16 + cl) * 64 + (((ks * 4 + g) ^ (cl & 7)) << 3)]);
        s[n] = __builtin_amdgcn_mfma_f32_16x16x32_bf16(kf, qf[ks], s[n], 0, 0, 0);
      }
    __builtin_amdgcn_s_setprio(0);

    // causal mask: kv = kv0+n*16+rg+rr, q = qt+wave*16+cl
    const bool diag = (kv0 == qt);
    if (diag) {
      const int qg = wave * 16 + cl;
      #pragma unroll
      for (int n = 0; n < 4; ++n)
        #pragma unroll
        for (int rr = 0; rr < 4; ++rr) {
          int kl = n * 16 + rg + rr;
          if (kl > qg) s[n][rr] = -1e30f;
        }
    }

    // ---- online softmax (all 16 in-lane values share q=cl) ----
    float mx = fmaxf(fmaxf(s[0][0], s[0][1]), fmaxf(s[0][2], s[0][3]));
    #pragma unroll
    for (int n = 1; n < 4; ++n)
      mx = fmaxf(mx, fmaxf(fmaxf(s[n][0], s[n][1]), fmaxf(s[n][2], s[n][3])));
    mx = fmaxf(mx, __shfl_xor(mx, 16));
    mx = fmaxf(mx, __shfl_xor(mx, 32));

    if (__any(mx > mrun)) {
      float mnew  = fmaxf(mrun, mx);
      float alpha = EXP2F(mrun - mnew);   // == 1 exactly where mx <= mrun
      mrun = mnew;
      float psum = 0.f;
      #pragma unroll
      for (int n = 0; n < 4; ++n)
        #pragma unroll
        for (int rr = 0; rr < 4; ++rr) {
          float p = EXP2F(s[n][rr] - mnew);
          s[n][rr] = p;
          psum += p;
        }
      lrun = lrun * alpha + psum;
      // redistribute alpha from q=cl orientation to q=rg+rr (oacc orientation)
      float ar[4];
      #pragma unroll
      for (int rr = 0; rr < 4; ++rr) ar[rr] = __shfl(alpha, (g << 4) + rg + rr);
      #pragma unroll
      for (int n = 0; n < 4; ++n)
        #pragma unroll
        for (int rr = 0; rr < 4; ++rr) oacc[n][rr] *= ar[rr];
    } else {   // alpha == 1 for every q in wave
      float psum = 0.f;
      #pragma unroll
      for (int n = 0; n < 4; ++n)
        #pragma unroll
        for (int rr = 0; rr < 4; ++rr) {
          float p = EXP2F(s[n][rr] - mrun);
          s[n][rr] = p;
          psum += p;
        }
      lrun += psum;
    }

    // ---- stage P^T -> Ps[q=cl][kv], 4x ds_write_b64, chunk' = n ^ (cl&3) ----
    #pragma unroll
    for (int n = 0; n < 4; ++n) {
      unsigned w0 = ((unsigned)f2bf_hw(s[n][1]) << 16) | f2bf_hw(s[n][0]);
      unsigned w1 = ((unsigned)f2bf_hw(s[n][3]) << 16) | f2bf_hw(s[n][2]);
      uint2 pk; pk.x = w0; pk.y = w1;
      *(uint2*)&Ps[wave][cl * 64 + ((n ^ (cl & 3)) << 4) + (g << 2)] = pk;
    }

    // ---- O += P @ V (pa read matches the Ps swizzle; vf unchanged) ----
    #pragma unroll
    for (int ks = 0; ks < 2; ++ks) {
      bf16x8 pa = ld_bf8(&Ps[wave][cl * 64 + (((ks * 2 + (g >> 1)) ^ (cl & 3)) << 4) + ((g & 1) << 3)]);
      __builtin_amdgcn_s_setprio(1);
      #pragma unroll
      for (int n = 0; n < 4; ++n) {
        bf16x8 vf = ld_bf8(&Vs[cur][(n * 16 + cl) * 64 + (((ks * 4 + g) ^ (cl & 7)) << 3)]);
        oacc[n] = __builtin_amdgcn_mfma_f32_16x16x32_bf16(pa, vf, oacc[n], 0, 0, 0);
      }
      __builtin_amdgcn_s_setprio(0);
    }

    __syncthreads();
  }

  // ---- final: reduce lrun across groups, redistribute to q=rg+rr, write ----
  lrun += __shfl_xor(lrun, 16);
  lrun += __shfl_xor(lrun, 32);
  float inv = 1.0f / lrun;
  float ir[4];
  #pragma unroll
  for (int rr = 0; rr < 4; ++rr) ir[rr] = __shfl(inv, (g << 4) + rg + rr);
  #pragma unroll
  for (int rr = 0; rr < 4; ++rr) {
    int t = qt + wave * 16 + rg + rr;
    size_t rowo = ((size_t)b * Tn + t) * Cn + h * Dn;
    #pragma unroll
    for (int n = 0; n < 4; ++n)
      outb[rowo + n * 16 + cl] = f2bf_hw(oacc[n][rr] * ir[rr]);
  }
}

extern "C" void kernel_launch(void* const* d_in, const int* in_sizes, int n_in,
                              void* d_out, int out_size, void* d_ws, size_t ws_size,
                              hipStream_t stream) {
  const float* x    = (const float*)d_in[0];
  const float* Wqkv = (const float*)d_in[1];
  const float* Wout = (const float*)d_in[2];
  float* y = (float*)d_out;

  unsigned short* xb    = (unsigned short*)d_ws;
  unsigned short* wqkvb = xb    + (size_t)Bn * Tn * Cn;
  unsigned short* woutb = wqkvb + (size_t)3 * Cn * Cn;
  unsigned short* qkvb  = woutb + (size_t)Cn * Cn;
  unsigned short* vtb   = qkvb  + (size_t)Bn * Tn * 3 * Cn;

  const int M = Bn * Tn;  // 8192

  {
    int n4 = (Bn * Tn * Cn) / 4;
    cvt_kernel<<<(n4 + 255) / 256, 256, 0, stream>>>(x, xb, n4);
  }
  {
    int n4 = (3 * Cn * Cn) / 4;
    cvt_kernel<<<(n4 + 255) / 256, 256, 0, stream>>>(Wqkv, wqkvb, n4);
  }
  {
    int n4 = (Cn * Cn) / 4;
    cvt_kernel<<<(n4 + 255) / 256, 256, 0, stream>>>(Wout, woutb, n4);
  }

  gemm_bt<2><<<dim3(3 * Cn / 128, M / 128), 256, 0, stream>>>(xb, wqkvb, qkvb, vtb, M, 3 * Cn, Cn);
  attn_kernel<<<dim3(Tn / 64, Bn * Hn), 256, 0, stream>>>(qkvb, vtb, xb);
  gemm_bt<0><<<dim3(Cn / 128, M / 128), 256, 0, stream>>>(xb, woutb, y, nullptr, M, Cn, Cn);

  (void)in_sizes; (void)n_in; (void)out_size; (void)ws_size;
}